// Round 12
// baseline (148.650 us; speedup 1.0000x reference)
//
#include <hip/hip_runtime.h>
#include <math.h>

// SO3 convolution lmax=2 — memset + prep(bucket+cgsort) + ONE main kernel.
//   K0) hipMemsetAsync(cnt) — tiny.
//   K1) prep_kernel: buckets edges by destination atom (1 atomic + 1 store
//       per edge); last block counting-sorts the sparse-CG entries by output
//       cell (cell = i3*9+i1, 81 cells) -> cellOff/cellDat.
//   K2) so3_main: grid = A, 256 thr = 4 waves. Wave w processes bucket edges
//       w, w+4, ... — ONE FULL EDGE PER WAVE PER ROUND (R8's proven
//       high-occupancy shape: short dependent chain, low VGPR) with:
//         * Y -> wave-private LDS (lane 0), M[9x12] built per-cell in
//           REGISTERS from block-shared sorted cg tables (no atomics,
//           no zero-init), radial filter via per-edge Wf pass (Wf addresses
//           static -> loads pipeline ahead of the e-chain), x[j] gather,
//           9x9 contract, register accumulate across rounds.
//       Epilogue: waves 1-3 dump acc -> LDS, wave 0 sums + ONE plain store
//       per atom (deg-0 -> zeros). Work scales with real edges; no slots,
//       no reduce dispatch, no global atomics.
//   Fallback (ncg > MAXCG or ws too small): R8 fused-atomic edge kernel.

#define S9     9
#define MROW   12
#define MSZ    (S9 * MROW)      // 108
#define NF     128
#define NRAD   20
#define WPB    4                // waves (edges in flight) per block
#define CAP    64
#define NCELL  81
#define MAXCG  512

__device__ inline float2 f2fma(float a, float2 b, float2 c) {
    return make_float2(fmaf(a, b.x, c.x), fmaf(a, b.y, c.y));
}

// ---------- K1: bucket scatter + cg cell-sort ----------
__global__ __launch_bounds__(256) void prep_kernel(
    const int* __restrict__ idx_i, int E, int nbuck,
    const int* __restrict__ cg_i1, const int* __restrict__ cg_i2,
    const int* __restrict__ cg_i3, const float* __restrict__ cg_vals, int ncg,
    int* __restrict__ cnt,          // [A], pre-zeroed
    int* __restrict__ buck,         // [A*CAP]
    int* __restrict__ cellOff,      // [NCELL+1]
    int2* __restrict__ cellDat)     // [ncg] (s2, bits(val)) grouped by cell
{
    const int t = threadIdx.x;
    if ((int)blockIdx.x < nbuck) {
        int e = blockIdx.x * 256 + t;
        if (e < E) {
            int a = idx_i[e];
            int p = atomicAdd(&cnt[a], 1);
            if (p < CAP) buck[a * CAP + p] = e;
        }
        return;
    }
    __shared__ int hist[NCELL];
    __shared__ int cur[NCELL];
    if (t < NCELL) hist[t] = 0;
    __syncthreads();
    for (int k = t; k < ncg; k += 256)
        atomicAdd(&hist[cg_i3[k] * S9 + cg_i1[k]], 1);
    __syncthreads();
    if (t == 0) {
        int run = 0;
        for (int c = 0; c < NCELL; ++c) {
            cellOff[c] = run; cur[c] = run; run += hist[c];
        }
        cellOff[NCELL] = run;
    }
    __syncthreads();
    for (int k = t; k < ncg; k += 256) {
        int cell = cg_i3[k] * S9 + cg_i1[k];
        int p = atomicAdd(&cur[cell], 1);
        cellDat[p] = make_int2(cg_i2[k], __float_as_int(cg_vals[k]));
    }
}

// ---------- K2: one block per atom, one edge per wave per round ----------
__global__ __launch_bounds__(256, 4) void so3_main(
    const float* __restrict__ x,        // [A, 9, 128]
    const float* __restrict__ radial,   // [E, 20]
    const float* __restrict__ dir,      // [E, 3]
    const float* __restrict__ cutoff,   // [E]
    const float* __restrict__ Wf,       // [20, 384]
    const float* __restrict__ bf,       // [384]
    const int* __restrict__ idx_j,
    const int* __restrict__ cnt,        // [A]
    const int* __restrict__ buck,       // [A*CAP]
    const int* __restrict__ cellOff,    // [NCELL+1]
    const int2* __restrict__ cellDat,   // [ncg]
    int ncg,
    float* __restrict__ out)            // [A, 9, 128]
{
    const int a    = blockIdx.x;
    const int t    = threadIdx.x;
    const int lane = t & 63;             // f-pair index: f = 2*lane, 2*lane+1
    const int wid  = t >> 6;

    __shared__ int   offsh[NCELL + 1];
    __shared__ int2  datsh[MAXCG];
    __shared__ __align__(16) float Msh[WPB][MSZ];   // 1728 B, wave-private
    __shared__ float Ysh[WPB][S9];
    __shared__ float red[WPB - 1][S9 * NF];         // 13824 B

    const int deg = min(cnt[a], CAP);

    // block-shared cg tables (the only pre-loop barrier)
    for (int k = t; k <= NCELL; k += 256) offsh[k] = cellOff[k];
    for (int k = t; k < ncg; k += 256) datsh[k] = cellDat[k];
    __syncthreads();

    float2 acc[S9];
    #pragma unroll
    for (int s = 0; s < S9; ++s) acc[s] = make_float2(0.f, 0.f);

    const float2 b0 = ((const float2*)(bf + 0 * NF))[lane];
    const float2 b1 = ((const float2*)(bf + 1 * NF))[lane];
    const float2 b2 = ((const float2*)(bf + 2 * NF))[lane];

    // each wave: edges wid, wid+4, ... (no barriers; wave-private LDS)
    for (int p = wid; p < deg; p += WPB) {
        const int e = buck[a * CAP + p];             // wave-uniform
        const int j = __builtin_amdgcn_readfirstlane(idx_j[e]);
        const float cut = cutoff[e];

        // Y -> wave-private LDS (same-wave DS ordering; no barrier needed)
        {
            float dx = dir[3 * e], dy = dir[3 * e + 1], dz = dir[3 * e + 2];
            const float inv = rsqrtf(dx * dx + dy * dy + dz * dz);
            dx *= inv; dy *= inv; dz *= inv;
            if (lane == 0) {
                const float s3c  = 1.7320508075688772f;
                const float s5c  = 2.2360679774997896f;
                const float s15c = 3.8729833462074170f;
                Ysh[wid][0] = 1.0f;
                Ysh[wid][1] = s3c * dy;
                Ysh[wid][2] = s3c * dz;
                Ysh[wid][3] = s3c * dx;
                Ysh[wid][4] = s15c * dx * dy;
                Ysh[wid][5] = s15c * dy * dz;
                Ysh[wid][6] = 0.5f * s5c * (3.0f * dz * dz - 1.0f);
                Ysh[wid][7] = s15c * dx * dz;
                Ysh[wid][8] = 0.5f * s15c * (dx * dx - dy * dy);
            }
        }

        // radial rows (uniform-address broadcast loads)
        float rad[NRAD];
        #pragma unroll
        for (int r = 0; r < NRAD; ++r) rad[r] = radial[(size_t)e * NRAD + r];

        // B1: per-edge radial filter (Wf addresses static -> pipelines early)
        float2 w0 = b0, w1 = b1, w2 = b2;
        #pragma unroll 4
        for (int r = 0; r < NRAD; ++r) {
            const float2* wrow = (const float2*)(Wf + r * (3 * NF));
            w0 = f2fma(rad[r], wrow[lane],       w0);
            w1 = f2fma(rad[r], wrow[lane + 64],  w1);
            w2 = f2fma(rad[r], wrow[lane + 128], w2);
        }
        w0.x *= cut; w0.y *= cut;
        w1.x *= cut; w1.y *= cut;
        w2.x *= cut; w2.y *= cut;

        // M-build: per-cell register FMA from sorted cg (no atomics)
        #pragma unroll
        for (int cc = 0; cc < 2; ++cc) {
            const int cell = lane + cc * 64;
            if (cell < NCELL) {
                const int s3i = cell / 9;
                const int s1i = cell - 9 * s3i;
                const int o0 = offsh[cell], o1 = offsh[cell + 1];
                float m = 0.f;
                for (int idx = o0; idx < o1; ++idx) {
                    const int2 d = datsh[idx];
                    m = fmaf(__int_as_float(d.y), Ysh[wid][d.x], m);
                }
                Msh[wid][s3i * MROW + s1i] = m;
            }
        }

        // gather x[j]
        const float2* xp = (const float2*)(x + (size_t)j * (S9 * NF)) + lane;
        float2 xj[S9];
        #pragma unroll
        for (int s = 0; s < S9; ++s) xj[s] = xp[s * 64];

        // contract (M reads are wave-uniform -> LDS broadcast)
        #pragma unroll
        for (int s3 = 0; s3 < S9; ++s3) {
            const float4* mr = (const float4*)&Msh[wid][s3 * MROW];
            const float4 m0 = mr[0];
            const float4 m1 = mr[1];
            const float  m8 = Msh[wid][s3 * MROW + 8];
            float2 tsum = make_float2(0.f, 0.f);
            tsum = f2fma(m0.x, xj[0], tsum);
            tsum = f2fma(m0.y, xj[1], tsum);
            tsum = f2fma(m0.z, xj[2], tsum);
            tsum = f2fma(m0.w, xj[3], tsum);
            tsum = f2fma(m1.x, xj[4], tsum);
            tsum = f2fma(m1.y, xj[5], tsum);
            tsum = f2fma(m1.z, xj[6], tsum);
            tsum = f2fma(m1.w, xj[7], tsum);
            tsum = f2fma(m8,   xj[8], tsum);
            const float2 wl = (s3 == 0) ? w0 : ((s3 < 4) ? w1 : w2);
            acc[s3].x = fmaf(wl.x, tsum.x, acc[s3].x);
            acc[s3].y = fmaf(wl.y, tsum.y, acc[s3].y);
        }
    }

    // ---- cross-wave reduce + single plain store (deg-0 -> zeros) ----
    if (wid > 0) {
        float2* rp = (float2*)&red[wid - 1][0];
        #pragma unroll
        for (int s = 0; s < S9; ++s) rp[s * 64 + lane] = acc[s];
    }
    __syncthreads();
    if (wid == 0) {
        #pragma unroll
        for (int r2 = 0; r2 < WPB - 1; ++r2) {
            const float2* rp = (const float2*)&red[r2][0];
            #pragma unroll
            for (int s = 0; s < S9; ++s) {
                float2 v = rp[s * 64 + lane];
                acc[s].x += v.x; acc[s].y += v.y;
            }
        }
        float2* op = (float2*)(out + (size_t)a * (S9 * NF)) + lane;
        #pragma unroll
        for (int s = 0; s < S9; ++s) op[s * 64] = acc[s];
    }
}

// ---------- fallback: R8 fused edge kernel with global atomics ----------
__global__ __launch_bounds__(256) void so3_edge_fused(
    const float* __restrict__ x, const float* __restrict__ radial,
    const float* __restrict__ dir, const float* __restrict__ cutoff,
    const float* __restrict__ Wf, const float* __restrict__ bf,
    const float* __restrict__ cg_vals,
    const int* __restrict__ idx_i, const int* __restrict__ idx_j,
    const int* __restrict__ cg_i1, const int* __restrict__ cg_i2,
    const int* __restrict__ cg_i3, int ncg, int E,
    float* __restrict__ out)
{
    const int wid  = threadIdx.x >> 6;
    const int lane = threadIdx.x & 63;
    const int e = blockIdx.x * 4 + wid;
    if (e >= E) return;

    __shared__ __align__(16) float Msh[4][MSZ];
    __shared__ float Ysh[4][S9];

    if (lane < 27) ((float4*)&Msh[wid][0])[lane] = make_float4(0.f, 0.f, 0.f, 0.f);

    float dx = dir[3 * e], dy = dir[3 * e + 1], dz = dir[3 * e + 2];
    const float inv = rsqrtf(dx * dx + dy * dy + dz * dz);
    dx *= inv; dy *= inv; dz *= inv;
    if (lane == 0) {
        const float s3c = 1.7320508075688772f, s5c = 2.2360679774997896f,
                    s15c = 3.8729833462074170f;
        Ysh[wid][0] = 1.0f;
        Ysh[wid][1] = s3c * dy; Ysh[wid][2] = s3c * dz; Ysh[wid][3] = s3c * dx;
        Ysh[wid][4] = s15c * dx * dy; Ysh[wid][5] = s15c * dy * dz;
        Ysh[wid][6] = 0.5f * s5c * (3.0f * dz * dz - 1.0f);
        Ysh[wid][7] = s15c * dx * dz;
        Ysh[wid][8] = 0.5f * s15c * (dx * dx - dy * dy);
    }
    for (int k = lane; k < ncg; k += 64)
        atomicAdd(&Msh[wid][cg_i3[k] * MROW + cg_i1[k]], cg_vals[k] * Ysh[wid][cg_i2[k]]);

    float rad[NRAD];
    #pragma unroll
    for (int r = 0; r < NRAD; ++r) rad[r] = radial[(size_t)e * NRAD + r];
    const float cut = cutoff[e];

    float2 w0 = ((const float2*)(bf + 0 * NF))[lane];
    float2 w1 = ((const float2*)(bf + 1 * NF))[lane];
    float2 w2 = ((const float2*)(bf + 2 * NF))[lane];
    #pragma unroll 4
    for (int r = 0; r < NRAD; ++r) {
        const float2* wrow = (const float2*)(Wf + r * (3 * NF));
        w0 = f2fma(rad[r], wrow[lane], w0);
        w1 = f2fma(rad[r], wrow[lane + 64], w1);
        w2 = f2fma(rad[r], wrow[lane + 128], w2);
    }
    w0.x *= cut; w0.y *= cut; w1.x *= cut; w1.y *= cut; w2.x *= cut; w2.y *= cut;

    const int j = __builtin_amdgcn_readfirstlane(idx_j[e]);
    const float2* xp = (const float2*)(x + (size_t)j * (S9 * NF)) + lane;
    float2 xj[S9];
    #pragma unroll
    for (int s = 0; s < S9; ++s) xj[s] = xp[s * 64];

    const int a = __builtin_amdgcn_readfirstlane(idx_i[e]);
    float* op = out + (size_t)a * (S9 * NF) + 2 * lane;
    #pragma unroll
    for (int s3 = 0; s3 < S9; ++s3) {
        const float4* mr = (const float4*)&Msh[wid][s3 * MROW];
        const float4 m0 = mr[0];
        const float4 m1 = mr[1];
        const float  m8 = Msh[wid][s3 * MROW + 8];
        float2 tsum = make_float2(0.f, 0.f);
        tsum = f2fma(m0.x, xj[0], tsum);
        tsum = f2fma(m0.y, xj[1], tsum);
        tsum = f2fma(m0.z, xj[2], tsum);
        tsum = f2fma(m0.w, xj[3], tsum);
        tsum = f2fma(m1.x, xj[4], tsum);
        tsum = f2fma(m1.y, xj[5], tsum);
        tsum = f2fma(m1.z, xj[6], tsum);
        tsum = f2fma(m1.w, xj[7], tsum);
        tsum = f2fma(m8,   xj[8], tsum);
        const float2 wl = (s3 == 0) ? w0 : ((s3 < 4) ? w1 : w2);
        atomicAdd(&op[s3 * NF],     wl.x * tsum.x);
        atomicAdd(&op[s3 * NF + 1], wl.y * tsum.y);
    }
}

extern "C" void kernel_launch(void* const* d_in, const int* in_sizes, int n_in,
                              void* d_out, int out_size, void* d_ws, size_t ws_size,
                              hipStream_t stream) {
    const float* x       = (const float*)d_in[0];
    const float* radial  = (const float*)d_in[1];
    const float* dir     = (const float*)d_in[2];
    const float* cutoff  = (const float*)d_in[3];
    const float* Wf      = (const float*)d_in[4];
    const float* bf      = (const float*)d_in[5];
    const float* cg_vals = (const float*)d_in[6];
    const int*   idx_i   = (const int*)d_in[7];
    const int*   idx_j   = (const int*)d_in[8];
    const int*   cg_i1   = (const int*)d_in[9];
    const int*   cg_i2   = (const int*)d_in[10];
    const int*   cg_i3   = (const int*)d_in[11];
    // d_in[12] = w_idx: unused (folded into kernel)

    const int E   = in_sizes[7];
    const int ncg = in_sizes[6];
    const int A   = in_sizes[0] / (S9 * NF);

    // ws: cnt[A] | cellOff[82] | buck[A*CAP] | (align) | cellDat[ncg]
    int* cnt      = (int*)d_ws;
    int* cellOff  = cnt + A;
    int* buck     = cellOff + (NCELL + 1);
    size_t ib     = (size_t)(A + NCELL + 1 + A * CAP) * sizeof(int);
    size_t doff   = (ib + 255) & ~(size_t)255;
    int2* cellDat = (int2*)((char*)d_ws + doff);
    size_t need   = doff + (size_t)ncg * sizeof(int2);

    if (ws_size >= need && ncg <= MAXCG) {
        hipMemsetAsync(cnt, 0, (size_t)A * sizeof(int), stream);

        const int nbuck = (E + 255) / 256;
        prep_kernel<<<nbuck + 1, 256, 0, stream>>>(
            idx_i, E, nbuck, cg_i1, cg_i2, cg_i3, cg_vals, ncg,
            cnt, buck, cellOff, cellDat);

        so3_main<<<A, 256, 0, stream>>>(
            x, radial, dir, cutoff, Wf, bf, idx_j,
            cnt, buck, cellOff, cellDat, ncg, (float*)d_out);
    } else {
        hipMemsetAsync(d_out, 0, (size_t)out_size * sizeof(float), stream);
        so3_edge_fused<<<(E + 3) / 4, 256, 0, stream>>>(
            x, radial, dir, cutoff, Wf, bf, cg_vals, idx_i, idx_j,
            cg_i1, cg_i2, cg_i3, ncg, E, (float*)d_out);
    }
}

// Round 13
// 131.755 us; speedup vs baseline: 1.1282x; 1.1282x over previous
//
#include <hip/hip_runtime.h>
#include <math.h>

// SO3 convolution lmax=2 — memset + prep(bucket+cgsort) + ONE main kernel.
//   K0) hipMemsetAsync(cnt) — tiny.
//   K1) prep_kernel: buckets edges by destination atom (1 atomic + 1 store
//       per edge); last block counting-sorts the sparse-CG entries by output
//       cell (cell = i3*9+i1, 81 cells) -> cellOff/cellDat.
//   K2) so3_main: grid = A, 256 thr = 4 waves, one full edge per wave per
//       round. R13 changes vs R12 (which spilled: VGPR capped 64 by
//       __launch_bounds__(256,4) -> 22 MB scratch stores seen in WRITE_SIZE):
//         * __launch_bounds__(256) only — no VGPR cap, no spills.
//         * e forced into SGPR via readfirstlane -> radial/cutoff/dir reads
//           become scalar-memory loads (rad[20] lives in SGPRs, shorter
//           VMEM chain, ~25 fewer VGPRs).
//       Per round: Y -> wave-private LDS, M[9x12] per-cell in registers from
//       block-shared sorted cg (no atomics), radial filter Wf pass, x[j]
//       gather, 9x9 contract, register accumulate. Epilogue: waves 1-3 dump
//       acc -> LDS, wave 0 sums + ONE plain store per atom (deg-0 -> zeros).
//       No slots, no reduce dispatch, no global atomics.
//   Fallback (ncg > MAXCG or ws too small): R8 fused-atomic edge kernel.

#define S9     9
#define MROW   12
#define MSZ    (S9 * MROW)      // 108
#define NF     128
#define NRAD   20
#define WPB    4                // waves (edges in flight) per block
#define CAP    64
#define NCELL  81
#define MAXCG  512

__device__ inline float2 f2fma(float a, float2 b, float2 c) {
    return make_float2(fmaf(a, b.x, c.x), fmaf(a, b.y, c.y));
}

// ---------- K1: bucket scatter + cg cell-sort ----------
__global__ __launch_bounds__(256) void prep_kernel(
    const int* __restrict__ idx_i, int E, int nbuck,
    const int* __restrict__ cg_i1, const int* __restrict__ cg_i2,
    const int* __restrict__ cg_i3, const float* __restrict__ cg_vals, int ncg,
    int* __restrict__ cnt,          // [A], pre-zeroed
    int* __restrict__ buck,         // [A*CAP]
    int* __restrict__ cellOff,      // [NCELL+1]
    int2* __restrict__ cellDat)     // [ncg] (s2, bits(val)) grouped by cell
{
    const int t = threadIdx.x;
    if ((int)blockIdx.x < nbuck) {
        int e = blockIdx.x * 256 + t;
        if (e < E) {
            int a = idx_i[e];
            int p = atomicAdd(&cnt[a], 1);
            if (p < CAP) buck[a * CAP + p] = e;
        }
        return;
    }
    __shared__ int hist[NCELL];
    __shared__ int cur[NCELL];
    if (t < NCELL) hist[t] = 0;
    __syncthreads();
    for (int k = t; k < ncg; k += 256)
        atomicAdd(&hist[cg_i3[k] * S9 + cg_i1[k]], 1);
    __syncthreads();
    if (t == 0) {
        int run = 0;
        for (int c = 0; c < NCELL; ++c) {
            cellOff[c] = run; cur[c] = run; run += hist[c];
        }
        cellOff[NCELL] = run;
    }
    __syncthreads();
    for (int k = t; k < ncg; k += 256) {
        int cell = cg_i3[k] * S9 + cg_i1[k];
        int p = atomicAdd(&cur[cell], 1);
        cellDat[p] = make_int2(cg_i2[k], __float_as_int(cg_vals[k]));
    }
}

// ---------- K2: one block per atom, one edge per wave per round ----------
__global__ __launch_bounds__(256) void so3_main(
    const float* __restrict__ x,        // [A, 9, 128]
    const float* __restrict__ radial,   // [E, 20]
    const float* __restrict__ dir,      // [E, 3]
    const float* __restrict__ cutoff,   // [E]
    const float* __restrict__ Wf,       // [20, 384]
    const float* __restrict__ bf,       // [384]
    const int* __restrict__ idx_j,
    const int* __restrict__ cnt,        // [A]
    const int* __restrict__ buck,       // [A*CAP]
    const int* __restrict__ cellOff,    // [NCELL+1]
    const int2* __restrict__ cellDat,   // [ncg]
    int ncg,
    float* __restrict__ out)            // [A, 9, 128]
{
    const int a    = blockIdx.x;
    const int t    = threadIdx.x;
    const int lane = t & 63;             // f-pair index: f = 2*lane, 2*lane+1
    const int wid  = t >> 6;

    __shared__ int   offsh[NCELL + 1];
    __shared__ int2  datsh[MAXCG];
    __shared__ __align__(16) float Msh[WPB][MSZ];   // wave-private
    __shared__ float Ysh[WPB][S9];
    __shared__ float red[WPB - 1][S9 * NF];

    const int deg = min(cnt[a], CAP);

    // block-shared cg tables (the only pre-loop barrier)
    for (int k = t; k <= NCELL; k += 256) offsh[k] = cellOff[k];
    for (int k = t; k < ncg; k += 256) datsh[k] = cellDat[k];
    __syncthreads();

    float2 acc[S9];
    #pragma unroll
    for (int s = 0; s < S9; ++s) acc[s] = make_float2(0.f, 0.f);

    const float2 b0 = ((const float2*)(bf + 0 * NF))[lane];
    const float2 b1 = ((const float2*)(bf + 1 * NF))[lane];
    const float2 b2 = ((const float2*)(bf + 2 * NF))[lane];

    // each wave: edges wid, wid+4, ... (no barriers; wave-private LDS)
    for (int p = wid; p < deg; p += WPB) {
        // e in SGPR -> radial/cutoff/dir become scalar-memory loads
        const int e = __builtin_amdgcn_readfirstlane(buck[a * CAP + p]);
        const int j = __builtin_amdgcn_readfirstlane(idx_j[e]);
        const float cut = cutoff[e];

        // Y -> wave-private LDS (same-wave DS ordering; no barrier needed)
        {
            float dx = dir[3 * e], dy = dir[3 * e + 1], dz = dir[3 * e + 2];
            const float inv = rsqrtf(dx * dx + dy * dy + dz * dz);
            dx *= inv; dy *= inv; dz *= inv;
            if (lane == 0) {
                const float s3c  = 1.7320508075688772f;
                const float s5c  = 2.2360679774997896f;
                const float s15c = 3.8729833462074170f;
                Ysh[wid][0] = 1.0f;
                Ysh[wid][1] = s3c * dy;
                Ysh[wid][2] = s3c * dz;
                Ysh[wid][3] = s3c * dx;
                Ysh[wid][4] = s15c * dx * dy;
                Ysh[wid][5] = s15c * dy * dz;
                Ysh[wid][6] = 0.5f * s5c * (3.0f * dz * dz - 1.0f);
                Ysh[wid][7] = s15c * dx * dz;
                Ysh[wid][8] = 0.5f * s15c * (dx * dx - dy * dy);
            }
        }

        // radial rows: uniform address (SGPR base) -> scalar loads, no VGPR cost
        float rad[NRAD];
        #pragma unroll
        for (int r = 0; r < NRAD; ++r) rad[r] = radial[(size_t)e * NRAD + r];

        // B1: per-edge radial filter (Wf addresses static -> pipeline early)
        float2 w0 = b0, w1 = b1, w2 = b2;
        #pragma unroll 4
        for (int r = 0; r < NRAD; ++r) {
            const float2* wrow = (const float2*)(Wf + r * (3 * NF));
            w0 = f2fma(rad[r], wrow[lane],       w0);
            w1 = f2fma(rad[r], wrow[lane + 64],  w1);
            w2 = f2fma(rad[r], wrow[lane + 128], w2);
        }
        w0.x *= cut; w0.y *= cut;
        w1.x *= cut; w1.y *= cut;
        w2.x *= cut; w2.y *= cut;

        // M-build: per-cell register FMA from sorted cg (no atomics)
        #pragma unroll
        for (int cc = 0; cc < 2; ++cc) {
            const int cell = lane + cc * 64;
            if (cell < NCELL) {
                const int s3i = cell / 9;
                const int s1i = cell - 9 * s3i;
                const int o0 = offsh[cell], o1 = offsh[cell + 1];
                float m = 0.f;
                for (int idx = o0; idx < o1; ++idx) {
                    const int2 d = datsh[idx];
                    m = fmaf(__int_as_float(d.y), Ysh[wid][d.x], m);
                }
                Msh[wid][s3i * MROW + s1i] = m;
            }
        }

        // gather x[j]
        const float2* xp = (const float2*)(x + (size_t)j * (S9 * NF)) + lane;
        float2 xj[S9];
        #pragma unroll
        for (int s = 0; s < S9; ++s) xj[s] = xp[s * 64];

        // contract (M reads wave-uniform -> LDS broadcast)
        #pragma unroll
        for (int s3 = 0; s3 < S9; ++s3) {
            const float4* mr = (const float4*)&Msh[wid][s3 * MROW];
            const float4 m0 = mr[0];
            const float4 m1 = mr[1];
            const float  m8 = Msh[wid][s3 * MROW + 8];
            float2 tsum = make_float2(0.f, 0.f);
            tsum = f2fma(m0.x, xj[0], tsum);
            tsum = f2fma(m0.y, xj[1], tsum);
            tsum = f2fma(m0.z, xj[2], tsum);
            tsum = f2fma(m0.w, xj[3], tsum);
            tsum = f2fma(m1.x, xj[4], tsum);
            tsum = f2fma(m1.y, xj[5], tsum);
            tsum = f2fma(m1.z, xj[6], tsum);
            tsum = f2fma(m1.w, xj[7], tsum);
            tsum = f2fma(m8,   xj[8], tsum);
            const float2 wl = (s3 == 0) ? w0 : ((s3 < 4) ? w1 : w2);
            acc[s3].x = fmaf(wl.x, tsum.x, acc[s3].x);
            acc[s3].y = fmaf(wl.y, tsum.y, acc[s3].y);
        }
    }

    // ---- cross-wave reduce + single plain store (deg-0 -> zeros) ----
    if (wid > 0) {
        float2* rp = (float2*)&red[wid - 1][0];
        #pragma unroll
        for (int s = 0; s < S9; ++s) rp[s * 64 + lane] = acc[s];
    }
    __syncthreads();
    if (wid == 0) {
        #pragma unroll
        for (int r2 = 0; r2 < WPB - 1; ++r2) {
            const float2* rp = (const float2*)&red[r2][0];
            #pragma unroll
            for (int s = 0; s < S9; ++s) {
                float2 v = rp[s * 64 + lane];
                acc[s].x += v.x; acc[s].y += v.y;
            }
        }
        float2* op = (float2*)(out + (size_t)a * (S9 * NF)) + lane;
        #pragma unroll
        for (int s = 0; s < S9; ++s) op[s * 64] = acc[s];
    }
}

// ---------- fallback: R8 fused edge kernel with global atomics ----------
__global__ __launch_bounds__(256) void so3_edge_fused(
    const float* __restrict__ x, const float* __restrict__ radial,
    const float* __restrict__ dir, const float* __restrict__ cutoff,
    const float* __restrict__ Wf, const float* __restrict__ bf,
    const float* __restrict__ cg_vals,
    const int* __restrict__ idx_i, const int* __restrict__ idx_j,
    const int* __restrict__ cg_i1, const int* __restrict__ cg_i2,
    const int* __restrict__ cg_i3, int ncg, int E,
    float* __restrict__ out)
{
    const int wid  = threadIdx.x >> 6;
    const int lane = threadIdx.x & 63;
    const int e = blockIdx.x * 4 + wid;
    if (e >= E) return;

    __shared__ __align__(16) float Msh[4][MSZ];
    __shared__ float Ysh[4][S9];

    if (lane < 27) ((float4*)&Msh[wid][0])[lane] = make_float4(0.f, 0.f, 0.f, 0.f);

    float dx = dir[3 * e], dy = dir[3 * e + 1], dz = dir[3 * e + 2];
    const float inv = rsqrtf(dx * dx + dy * dy + dz * dz);
    dx *= inv; dy *= inv; dz *= inv;
    if (lane == 0) {
        const float s3c = 1.7320508075688772f, s5c = 2.2360679774997896f,
                    s15c = 3.8729833462074170f;
        Ysh[wid][0] = 1.0f;
        Ysh[wid][1] = s3c * dy; Ysh[wid][2] = s3c * dz; Ysh[wid][3] = s3c * dx;
        Ysh[wid][4] = s15c * dx * dy; Ysh[wid][5] = s15c * dy * dz;
        Ysh[wid][6] = 0.5f * s5c * (3.0f * dz * dz - 1.0f);
        Ysh[wid][7] = s15c * dx * dz;
        Ysh[wid][8] = 0.5f * s15c * (dx * dx - dy * dy);
    }
    for (int k = lane; k < ncg; k += 64)
        atomicAdd(&Msh[wid][cg_i3[k] * MROW + cg_i1[k]], cg_vals[k] * Ysh[wid][cg_i2[k]]);

    float rad[NRAD];
    #pragma unroll
    for (int r = 0; r < NRAD; ++r) rad[r] = radial[(size_t)e * NRAD + r];
    const float cut = cutoff[e];

    float2 w0 = ((const float2*)(bf + 0 * NF))[lane];
    float2 w1 = ((const float2*)(bf + 1 * NF))[lane];
    float2 w2 = ((const float2*)(bf + 2 * NF))[lane];
    #pragma unroll 4
    for (int r = 0; r < NRAD; ++r) {
        const float2* wrow = (const float2*)(Wf + r * (3 * NF));
        w0 = f2fma(rad[r], wrow[lane], w0);
        w1 = f2fma(rad[r], wrow[lane + 64], w1);
        w2 = f2fma(rad[r], wrow[lane + 128], w2);
    }
    w0.x *= cut; w0.y *= cut; w1.x *= cut; w1.y *= cut; w2.x *= cut; w2.y *= cut;

    const int j = __builtin_amdgcn_readfirstlane(idx_j[e]);
    const float2* xp = (const float2*)(x + (size_t)j * (S9 * NF)) + lane;
    float2 xj[S9];
    #pragma unroll
    for (int s = 0; s < S9; ++s) xj[s] = xp[s * 64];

    const int a = __builtin_amdgcn_readfirstlane(idx_i[e]);
    float* op = out + (size_t)a * (S9 * NF) + 2 * lane;
    #pragma unroll
    for (int s3 = 0; s3 < S9; ++s3) {
        const float4* mr = (const float4*)&Msh[wid][s3 * MROW];
        const float4 m0 = mr[0];
        const float4 m1 = mr[1];
        const float  m8 = Msh[wid][s3 * MROW + 8];
        float2 tsum = make_float2(0.f, 0.f);
        tsum = f2fma(m0.x, xj[0], tsum);
        tsum = f2fma(m0.y, xj[1], tsum);
        tsum = f2fma(m0.z, xj[2], tsum);
        tsum = f2fma(m0.w, xj[3], tsum);
        tsum = f2fma(m1.x, xj[4], tsum);
        tsum = f2fma(m1.y, xj[5], tsum);
        tsum = f2fma(m1.z, xj[6], tsum);
        tsum = f2fma(m1.w, xj[7], tsum);
        tsum = f2fma(m8,   xj[8], tsum);
        const float2 wl = (s3 == 0) ? w0 : ((s3 < 4) ? w1 : w2);
        atomicAdd(&op[s3 * NF],     wl.x * tsum.x);
        atomicAdd(&op[s3 * NF + 1], wl.y * tsum.y);
    }
}

extern "C" void kernel_launch(void* const* d_in, const int* in_sizes, int n_in,
                              void* d_out, int out_size, void* d_ws, size_t ws_size,
                              hipStream_t stream) {
    const float* x       = (const float*)d_in[0];
    const float* radial  = (const float*)d_in[1];
    const float* dir     = (const float*)d_in[2];
    const float* cutoff  = (const float*)d_in[3];
    const float* Wf      = (const float*)d_in[4];
    const float* bf      = (const float*)d_in[5];
    const float* cg_vals = (const float*)d_in[6];
    const int*   idx_i   = (const int*)d_in[7];
    const int*   idx_j   = (const int*)d_in[8];
    const int*   cg_i1   = (const int*)d_in[9];
    const int*   cg_i2   = (const int*)d_in[10];
    const int*   cg_i3   = (const int*)d_in[11];
    // d_in[12] = w_idx: unused (folded into kernel)

    const int E   = in_sizes[7];
    const int ncg = in_sizes[6];
    const int A   = in_sizes[0] / (S9 * NF);

    // ws: cnt[A] | cellOff[82] | buck[A*CAP] | (align) | cellDat[ncg]
    int* cnt      = (int*)d_ws;
    int* cellOff  = cnt + A;
    int* buck     = cellOff + (NCELL + 1);
    size_t ib     = (size_t)(A + NCELL + 1 + A * CAP) * sizeof(int);
    size_t doff   = (ib + 255) & ~(size_t)255;
    int2* cellDat = (int2*)((char*)d_ws + doff);
    size_t need   = doff + (size_t)ncg * sizeof(int2);

    if (ws_size >= need && ncg <= MAXCG) {
        hipMemsetAsync(cnt, 0, (size_t)A * sizeof(int), stream);

        const int nbuck = (E + 255) / 256;
        prep_kernel<<<nbuck + 1, 256, 0, stream>>>(
            idx_i, E, nbuck, cg_i1, cg_i2, cg_i3, cg_vals, ncg,
            cnt, buck, cellOff, cellDat);

        so3_main<<<A, 256, 0, stream>>>(
            x, radial, dir, cutoff, Wf, bf, idx_j,
            cnt, buck, cellOff, cellDat, ncg, (float*)d_out);
    } else {
        hipMemsetAsync(d_out, 0, (size_t)out_size * sizeof(float), stream);
        so3_edge_fused<<<(E + 3) / 4, 256, 0, stream>>>(
            x, radial, dir, cutoff, Wf, bf, cg_vals, idx_i, idx_j,
            cg_i1, cg_i2, cg_i3, ncg, E, (float*)d_out);
    }
}